// Round 1
// baseline (111.582 us; speedup 1.0000x reference)
//
#include <hip/hip_runtime.h>
#include <math.h>

// SinusoidalPositionEmbeddings: out[i,j] = sin(t[i]*div(j)) if j even else cos(t[i]*div(j))
// div(j) = exp(-ln(10000) * (j - j%2) / (C-1)),  C = 1024, B = 131072.
// Memory-bound: 536.9 MB fp32 output stream; compute hides under stores.

#define EMBED_C 1024
#define C4 (EMBED_C / 4)   // 256 float4 per row

__global__ void __launch_bounds__(256)
sinembed_kernel(const float* __restrict__ t, float* __restrict__ out, int total4) {
    const int tid    = blockIdx.x * blockDim.x + threadIdx.x;
    const int stride = gridDim.x * blockDim.x;   // multiple of 256 -> col4 loop-invariant

    // coef = -log2(10000) / (C-1); div_term = 2^(coef * two_i)
    constexpr float coef = (float)(-13.287712379549449 / 1023.0);

    // This thread's 4 channels: j0, j0+1, j0+2, j0+3 (j0 = 4*col4, even).
    const int   col4 = tid & (C4 - 1);
    const int   j0   = col4 * 4;
    const float div0 = exp2f(coef * (float)j0);        // two_i for j0, j0+1
    const float div1 = exp2f(coef * (float)(j0 + 2));  // two_i for j0+2, j0+3

    for (int idx = tid; idx < total4; idx += stride) {
        const int   row = idx >> 8;        // idx / C4
        const float tv  = t[row];          // same addr across block -> broadcast, L2-hit

        float s0, c0, s1, c1;
        __sincosf(tv * div0, &s0, &c0);
        __sincosf(tv * div1, &s1, &c1);

        reinterpret_cast<float4*>(out)[idx] = make_float4(s0, c0, s1, c1);
    }
}

extern "C" void kernel_launch(void* const* d_in, const int* in_sizes, int n_in,
                              void* d_out, int out_size, void* d_ws, size_t ws_size,
                              hipStream_t stream) {
    const float* t   = (const float*)d_in[0];
    float*       out = (float*)d_out;

    const int total4 = out_size >> 2;            // 33,554,432 float4s
    const int block  = 256;
    int grid = 2048;                             // 8 blocks/CU territory; grid-stride the rest
    const int max_grid = (total4 + block - 1) / block;
    if (grid > max_grid) grid = max_grid;

    sinembed_kernel<<<grid, block, 0, stream>>>(t, out, total4);
}

// Round 2
// 97.445 us; speedup vs baseline: 1.1451x; 1.1451x over previous
//
#include <hip/hip_runtime.h>
#include <math.h>

// SinusoidalPositionEmbeddings: out[i,j] = sin(t[i]*div(j)) if j even else cos(t[i]*div(j))
// div(j) = exp(-ln(10000) * (j - j%2) / (C-1)),  C = 1024, B = 131072.
// Pure write-stream (536.9 MB fp32). Structure: 1 block = 4 rows, one uniform
// 16B t-load up front, then compute+store only (no per-iteration load chain).

#define EMBED_C 1024
#define C4 (EMBED_C / 4)      // 256 float4 per row
#define ROWS_PER_BLK 4

__global__ void __launch_bounds__(256)
sinembed_kernel(const float* __restrict__ t, float* __restrict__ out, int nrows) {
    const int tid = threadIdx.x;               // 0..255 == col4 index
    const int r0  = blockIdx.x * ROWS_PER_BLK; // first of 4 rows for this block

    // coef = -log2(10000) / (C-1); div_term = 2^(coef * two_i)
    constexpr float coef = (float)(-13.287712379549449 / 1023.0);
    const int   j0   = tid * 4;                            // even channel base
    const float div0 = exp2f(coef * (float)j0);            // channels j0, j0+1
    const float div1 = exp2f(coef * (float)(j0 + 2));      // channels j0+2, j0+3

    float4* o = reinterpret_cast<float4*>(out) + (size_t)r0 * C4 + tid;

    if (r0 + ROWS_PER_BLK <= nrows) {
        // Uniform 16B load (same addr across wave -> broadcast), issued once.
        const float4 tv = *reinterpret_cast<const float4*>(t + r0);
        const float tvals[ROWS_PER_BLK] = {tv.x, tv.y, tv.z, tv.w};

        #pragma unroll
        for (int k = 0; k < ROWS_PER_BLK; ++k) {
            float s0, c0, s1, c1;
            __sincosf(tvals[k] * div0, &s0, &c0);
            __sincosf(tvals[k] * div1, &s1, &c1);
            o[(size_t)k * C4] = make_float4(s0, c0, s1, c1);  // 1024B/wave coalesced
        }
    } else {
        // Tail guard (not hit for B=131072, kept for generality).
        for (int k = 0; k < ROWS_PER_BLK && (r0 + k) < nrows; ++k) {
            const float tvk = t[r0 + k];
            float s0, c0, s1, c1;
            __sincosf(tvk * div0, &s0, &c0);
            __sincosf(tvk * div1, &s1, &c1);
            o[(size_t)k * C4] = make_float4(s0, c0, s1, c1);
        }
    }
}

extern "C" void kernel_launch(void* const* d_in, const int* in_sizes, int n_in,
                              void* d_out, int out_size, void* d_ws, size_t ws_size,
                              hipStream_t stream) {
    const float* t   = (const float*)d_in[0];
    float*       out = (float*)d_out;

    const int nrows = out_size / EMBED_C;                      // 131072
    const int grid  = (nrows + ROWS_PER_BLK - 1) / ROWS_PER_BLK; // 32768 blocks

    sinembed_kernel<<<grid, 256, 0, stream>>>(t, out, nrows);
}